// Round 11
// baseline (615.874 us; speedup 1.0000x reference)
//
#include <hip/hip_runtime.h>
#include <hip/hip_bf16.h>
#include <math.h>

#define SEQ  512
#define BSZ  128
#define EMBD 128
#define HD   128
#define NTAG 7
#define BOSX 4
#define EOSX 5
#define NEGC (-10000.0f)

typedef _Float16 h2 __attribute__((ext_vector_type(2)));
typedef _Float16 f16x8 __attribute__((ext_vector_type(8)));
typedef float    f32x4 __attribute__((ext_vector_type(4)));

__device__ __forceinline__ float frcp(float x) { return __builtin_amdgcn_rcpf(x); }

// f16 dot2: 2 MACs/inst, fp32 accumulate (v_dot2_f32_f16)
__device__ __forceinline__ float fdot2(h2 a, h2 b, float c) {
#if __has_builtin(__builtin_amdgcn_fdot2)
    return __builtin_amdgcn_fdot2(a, b, c, false);
#else
    return c + (float)a.x * (float)b.x + (float)a.y * (float)b.y;
#endif
}

template<int C> __device__ __forceinline__ float dppaddf(float x) {
    const int y = __builtin_amdgcn_update_dpp(0, __builtin_bit_cast(int, x), C, 0xF, 0xF, true);
    return x + __builtin_bit_cast(float, y);
}
template<int C> __device__ __forceinline__ float dppmovf(float x) {
    return __builtin_bit_cast(float,
        __builtin_amdgcn_update_dpp(0, __builtin_bit_cast(int, x), C, 0xF, 0xF, true));
}
template<int C> __device__ __forceinline__ int dppmovi(int x) {
    return __builtin_amdgcn_update_dpp(0, x, C, 0xF, 0xF, true);
}
// sum over lane bits {0,1,2}: 2 quad_perm adds, then row_half_mirror
// (lane^7 == lane^4 once the value is quad-uniform -- vit-verified trick)
__device__ __forceinline__ float kreduce8(float x) {
    x = dppaddf<0xB1>(x);
    x = dppaddf<0x4E>(x);
    return x + dppmovf<0x141>(x);
}

// 16-element f16 chunk dot: w[8] half2 x x[8] half2 -> fp32
__device__ __forceinline__ float dot16h(const h2* __restrict__ w, const h2* __restrict__ x) {
    float a = 0.f;
    #pragma unroll
    for (int j = 0; j < 8; ++j) a = fdot2(w[j], x[j], a);
    return a;
}
// load 16 fp32 weights -> 8 half2 (RNE, one-time)
__device__ __forceinline__ void ldwh8(h2* w, const float4* wr) {
    #pragma unroll
    for (int j = 0; j < 4; ++j) {
        const float4 f4 = wr[j];
        h2 a; a.x = (_Float16)f4.x; a.y = (_Float16)f4.y;
        h2 b; b.x = (_Float16)f4.z; b.y = (_Float16)f4.w;
        w[2 * j] = a; w[2 * j + 1] = b;
    }
}
__device__ __forceinline__ void unp8(const uint4* p, h2* x) {
    #pragma unroll
    for (int j = 0; j < 2; ++j) {
        x[4 * j]     = __builtin_bit_cast(h2, p[j].x);
        x[4 * j + 1] = __builtin_bit_cast(h2, p[j].y);
        x[4 * j + 2] = __builtin_bit_cast(h2, p[j].z);
        x[4 * j + 3] = __builtin_bit_cast(h2, p[j].w);
    }
}

// lgkm-only step barrier (round-9/10 proven): LDS producers drain, global
// loads/stores stay in flight; sched_barrier fences pin order (rule #18).
__device__ __forceinline__ void step_barrier() {
    __builtin_amdgcn_sched_barrier(0);
    asm volatile("s_waitcnt lgkmcnt(0)" ::: "memory");
    __builtin_amdgcn_s_barrier();
    __builtin_amdgcn_sched_barrier(0);
}

// ========== K1: 16-wave TLP restructure (4 waves/SIMD) =======================
// Round-10 floor analysis: 2 waves/SIMD all session; at VGPR=128 the HW
// allows 4. 1024-thread block = 16 waves: 8 units/wave, 8-way K-split
// (k8 = lane&7, 16-elem chunks) -> 32 fdot2/lane/step (half of round-10),
// per-SIMD issue ~1000 -> ~700 cyc/step, and 4 waves interleave the serial
// chain instead of 2. Reduce-scatter: xor1 (0xB1) + xor2 (0x4E) as before,
// plus an xor4 stage done in-register: row_shl:4 / row_shr:4 DPP + cndmask
// (dst[i] = src[i^4], verified within-row for all lanes). NOTE: rounds 1-10
// had a 0x4E-for-0xB1 slip in the B stage (scrambled gates g/o partials,
// absmax 3->12); this kernel restores r0's verified 0xB1.
// proj = 2 MFMA tiles/wave (same 16 MFMA/step/CU total); zq ping-pong and
// lgkm-only barrier carried from round 10.
__global__ __launch_bounds__(1024) __attribute__((amdgpu_waves_per_eu(4, 4)))
void bilstm_fused(const int* __restrict__ sen, const float* __restrict__ emb,
                  const float* __restrict__ Wih_f, const float* __restrict__ b_f,
                  const float* __restrict__ Wih_b, const float* __restrict__ b_b,
                  const float* __restrict__ Whh_f, const float* __restrict__ Whh_b,
                  const float* __restrict__ W_out,
                  float* __restrict__ eft, float* __restrict__ ebt)
{
    const int tid = threadIdx.x;
    const int wid = tid >> 6;                              // 0..15
    const int lane = tid & 63;
    const int k8 = lane & 7;                               // K-chunk (16 elems)
    const int m8 = lane >> 3;                              // 0..7
    const int q  = lane & 3;                               // owned gate
    const int u  = wid * 8 + m8;                           // unit 0..127
    const bool bk0 = (lane & 1) != 0;
    const bool bk1 = (lane & 2) != 0;
    const bool bk2 = (lane & 4) != 0;
    const int col = lane & 15;                             // MFMA N-col / A-row
    const int kg  = lane >> 4;                             // MFMA K-group
    const int chain = blockIdx.x;
    const int dir = chain & 1;
    const int b = chain >> 1;
    const int t0 = dir ? (SEQ - 1) : 0;
    const int ts = dir ? -1 : 1;

    __shared__ __align__(16) _Float16 xA[2][4][4][16][8];  // x A-frag dbuf, 8 KB
    __shared__ __align__(16) float zb[2][8][512];          // z (proj+bias) dbuf, 32 KB
    __shared__ __align__(16) _Float16 hdb[2][128];         // h dbuf, 512 B

    const float* __restrict__ Wih  = dir ? Wih_b : Wih_f;
    const float* __restrict__ Whh  = dir ? Whh_b : Whh_f;
    const float* __restrict__ bias = dir ? b_b  : b_f;

    // recurrence weights: 4 gates x 16-elem chunk k8 of unit u (32 VGPR)
    h2 whh[4][8];
    #pragma unroll
    for (int g = 0; g < 4; ++g)
        ldwh8(whh[g], (const float4*)(Whh + (g * HD + u) * HD + k8 * 16));
    h2 wo[8];                                              // emission (wave 0)
    {
        const int mm = (m8 < NTAG) ? m8 : 0;
        ldwh8(wo, (const float4*)(W_out + mm * 256 + dir * HD + k8 * 16));
    }
    // projection B-frags: 2 tiles/wave, R=(wid*2+tt)*16+col  [r7-verified layout]
    f16x8 bw[2][4];
    float biasv[2];
    #pragma unroll
    for (int tt = 0; tt < 2; ++tt) {
        const int R = (wid * 2 + tt) * 16 + col;
        const int ug = R >> 2;
        const int gg = R & 3;
        #pragma unroll
        for (int ks = 0; ks < 4; ++ks) {
            const float* src = Wih + (gg * HD + ug) * EMBD + ks * 32 + kg * 8;
            f16x8 v;
            #pragma unroll
            for (int j = 0; j < 8; ++j) v[j] = (_Float16)src[j];
            bw[tt][ks] = v;
        }
        biasv[tt] = bias[gg * HD + ug];
    }

    if (tid < 128) ((unsigned*)hdb)[tid] = 0u;             // h=0 both buffers
    {   // zero xA (rows 8..15 never staged; keep MFMA inputs finite)
        unsigned* p = (unsigned*)xA;                       // 2048 dwords
        p[tid] = 0u; p[tid + 1024] = 0u;
    }

    // ---- x staging (waves 0-7 only): wave srow stages row 8w+srow ----
    const int srow = wid;
    const int sp = lane;
    float2 sv;
    auto sissue = [&](int w) {
        if (wid >= 8) return;
        const int row = w * 8 + srow;
        const int tg = t0 + ts * row;
        const int tok = sen[tg * BSZ + b];
        sv = *(const float2*)(emb + (size_t)tok * EMBD + 2 * sp);
    };
    auto swrite = [&](int buf) {
        if (wid >= 8) return;
        h2 t; t.x = (_Float16)sv.x; t.y = (_Float16)sv.y;
        *(unsigned*)&xA[buf][sp >> 4][(sp >> 2) & 3][srow][(sp & 3) * 2]
            = __builtin_bit_cast(unsigned, t);
    };

    // ---- batched projection: 8 MFMA/wave -> z rows 0..7 of buffer nb ----
    auto proj = [&](int bufp, int nb) {
        f16x8 ax[4];
        #pragma unroll
        for (int ks = 0; ks < 4; ++ks)
            ax[ks] = *(const f16x8*)&xA[bufp][ks][kg][col][0];
        f32x4 acc[2];
        #pragma unroll
        for (int tt = 0; tt < 2; ++tt) { acc[tt][0]=0.f; acc[tt][1]=0.f; acc[tt][2]=0.f; acc[tt][3]=0.f; }
        #pragma unroll
        for (int ks = 0; ks < 4; ++ks)
            #pragma unroll
            for (int tt = 0; tt < 2; ++tt)
                acc[tt] = __builtin_amdgcn_mfma_f32_16x16x32_f16(ax[ks], bw[tt][ks], acc[tt], 0, 0, 0);
        if (lane < 32) {                                   // D rows 0..7 = time rows
            #pragma unroll
            for (int tt = 0; tt < 2; ++tt)
                #pragma unroll
                for (int r = 0; r < 4; ++r)
                    zb[nb][(lane >> 4) * 4 + r][wid * 32 + tt * 16 + col]
                        = acc[tt][r] + biasv[tt];
        }
    };

    float c = 0.0f, v0 = 0.0f, v1 = 0.0f;
    float zqA, zqB;                                        // z ping-pong regs
    float* __restrict__ eX = (dir ? ebt : eft) + (size_t)b * (SEQ * 8);
    const int zrow = wid * 32 + m8 * 4 + q;                // gate-row u*4+q

    // ---- prologue ----
    sissue(0); swrite(0);
    sissue(1); swrite(1);
    __syncthreads();
    proj(0, 0);                                            // z rows 0..7
    sissue(2);
    __syncthreads();
    zqA = zb[0][0][zrow];                                  // z for step 0

    // ---- main loop: 64 blocks of 8 steps, one lgkm-only barrier/step ----
    for (int base = 0; base < SEQ; base += 8) {
        const int W = base >> 3;
        #pragma unroll
        for (int sl = 0; sl < 8; ++sl) {
            const int s = base + sl;
            const int cur = sl & 1;                        // base even -> s&1 == sl&1
            // h-read: 16B at chunk k8 (2-way bank alias = free; 8-lane bcast)
            uint4 hpk[2];
            {
                const uint4* hr = (const uint4*)&hdb[cur][k8 * 16];
                hpk[0] = hr[0]; hpk[1] = hr[1];
            }
            if (sl == 0) {
                if (base <= SEQ - 24) swrite(W & 1);       // window W+2 -> buf W&1
                if (base <= SEQ - 32) sissue(W + 3);       // rows [base+24,base+32)
                if (W < 63) proj((W & 1) ^ 1, (W & 1) ^ 1);// z rows base+8..15
            }
            const float xq = (sl & 1) ? zqB : zqA;         // z for THIS step
            if (s + 1 < SEQ) {                             // prefetch z for s+1
                const int nbuf = (sl == 7) ? ((W & 1) ^ 1) : (W & 1);
                const int nsl = (sl + 1) & 7;
                const float zn = zb[nbuf][nsl][zrow];
                if (sl & 1) zqA = zn; else zqB = zn;
            }
            // recurrence: 32 fdot2 + 3-stage reduce-scatter
            h2 hx[8];
            unp8(hpk, hx);
            {
                const float pi = dot16h(whh[0], hx);
                const float pf = dot16h(whh[1], hx);
                const float pg = dot16h(whh[2], hx);
                const float po = dot16h(whh[3], hx);
                // stage 1 (xor1): gate pairs i/f and g/o  [0xB1 in BOTH -- r0-correct]
                const float A = (bk0 ? pf : pi) + dppmovf<0xB1>(bk0 ? pi : pf);
                const float B = (bk0 ? po : pg) + dppmovf<0xB1>(bk0 ? pg : po);
                // stage 2 (xor2): scatter 4 gates over lane bits 0-1
                const float z1 = (bk1 ? B : A) + dppmovf<0x4E>(bk1 ? A : B);
                // stage 3 (xor4): pure add of same-gate halves; dst[i]=src[i^4]
                // via row_shl:4 (0x104, i-4) for bit2=1, row_shr:4 (0x114, i+4)
                // for bit2=0 -- all within-row accesses valid.
                const float zs = bk2 ? dppmovf<0x104>(z1) : dppmovf<0x114>(z1);
                float z = z1 + zs + xq;
                // one activation per lane (gate 2 = tanh via 2*sigma(2z)-1)
                const bool isg = bk1 && !bk0;              // q == 2
                const float x2 = isg ? (z + z) : z;
                float y = frcp(1.0f + __expf(-x2));
                y = isg ? (2.0f * y - 1.0f) : y;
                // all-gather 4 gates within quad (both bit2-halves identical)
                const float r1 = dppmovf<0xB1>(y);
                const float r2 = dppmovf<0x4E>(y);
                const float r3 = dppmovf<0x4E>(r1);
                const float i0 = bk0 ? r1 : y,  i1 = bk0 ? y : r1;
                const float i2 = bk0 ? r3 : r2, i3 = bk0 ? r2 : r3;
                const float gi = bk1 ? i2 : i0;
                const float gf = bk1 ? i3 : i1;
                const float gg2 = bk1 ? i0 : i2;
                const float go = bk1 ? i1 : i3;
                c = gf * c + gi * gg2;                     // redundant x8 over k8
                const float th = 2.0f * frcp(1.0f + __expf(-2.0f * c)) - 1.0f;
                const float h = go * th;
                if (k8 == 0)                               // unit u's h (f16)
                    hdb[cur ^ 1][u] = (_Float16)h;
            }
            if (wid == 0 && s >= 1) {                      // emission for e = s-1
                const float ev = kreduce8(dot16h(wo, hx));
                const int e = s - 1;
                const bool mine = (e & 7) == k8;           // e uniform, k8 lane-varying
                const int j = (e >> 3) & 1;
                v0 = (mine && j == 0) ? ev : v0;
                v1 = (mine && j == 1) ? ev : v1;
                if ((s & 15) == 0 && m8 < NTAG) {          // flush e in [s-16, s-1]
                    const int eA = s - 16 + k8;
                    eX[(t0 + ts * (eA + 0)) * 8 + m8] = v0;
                    eX[(t0 + ts * (eA + 8)) * 8 + m8] = v1;
                }
            }
            step_barrier();
        }
    }

    // ---- epilogue: emission e = SEQ-1 from h(SEQ-1) (in hdb[0]) + flush ----
    if (wid == 0) {
        uint4 hpk[2];
        const uint4* hr = (const uint4*)&hdb[0][k8 * 16];
        hpk[0] = hr[0]; hpk[1] = hr[1];
        h2 hx[8];
        unp8(hpk, hx);
        const float ev = kreduce8(dot16h(wo, hx));
        if (k8 == 7) v1 = ev;                              // e=511: (e&7)=7, j=1
        if (m8 < NTAG) {
            const int eA = SEQ - 16 + k8;
            eX[(t0 + ts * (eA + 0)) * 8 + m8] = v0;
            eX[(t0 + ts * (eA + 8)) * 8 + m8] = v1;
        }
    }
}

// ======================= K2: Viterbi scan + backtrace =======================
// (verbatim round-4 kernel: DPP butterfly argmax, OR-packed 3-bit
// backpointer words, readlane-only bit-chase backtrace)
__global__ __launch_bounds__(256, 1)
void vit_kernel(const float* __restrict__ eft, const float* __restrict__ ebt,
                const float* __restrict__ b_out, const float* __restrict__ trans,
                float* __restrict__ out)
{
    const int b = blockIdx.x;
    const int tid = threadIdx.x;
    __shared__ __align__(16) float ftl[SEQ * 8];
    __shared__ unsigned wordL[SEQ];                        // packed backpointers

    {   // stage ef+eb with all 256 threads
        const float4* sf = (const float4*)(eft + (size_t)b * (SEQ * 8));
        const float4* sb = (const float4*)(ebt + (size_t)b * (SEQ * 8));
        float4* dst = (float4*)ftl;
        #pragma unroll
        for (int i = 0; i < SEQ * 2 / 256; ++i) {
            const int idx = tid + i * 256;
            float4 a = sf[idx];
            const float4 c4 = sb[idx];
            a.x += c4.x; a.y += c4.y; a.z += c4.z; a.w += c4.w;
            dst[idx] = a;
        }
    }
    __syncthreads();

    if (tid < 64) {
        const int lane = tid;
        const int next = lane >> 3;
        const int prev = lane & 7;
        const bool pv = (prev < NTAG);
        const bool nv = (next < NTAG);
        const float trv = (pv && nv) ? (trans[next * NTAG + prev] + b_out[next]) : -3.0e38f;
        float fvp = pv ? ((prev == BOSX) ? 0.0f : NEGC) : -3.0e38f;

        for (int t = 0; t < SEQ; ++t) {
            float mv = fvp + trv;
            int am = prev;
            {   // xor1 (quad_perm)
                const float om = dppmovf<0xB1>(mv); const int oa = dppmovi<0xB1>(am);
                if (om > mv || (om == mv && oa < am)) { mv = om; am = oa; }
            }
            {   // xor2 (quad_perm)
                const float om = dppmovf<0x4E>(mv); const int oa = dppmovi<0x4E>(am);
                if (om > mv || (om == mv && oa < am)) { mv = om; am = oa; }
            }
            {   // quad-pair via row_half_mirror (value quad-uniform by now)
                const float om = dppmovf<0x141>(mv); const int oa = dppmovi<0x141>(am);
                if (om > mv || (om == mv && oa < am)) { mv = om; am = oa; }
            }
            const float fvnew = mv + ftl[t * 8 + next];
            const float nfv = __shfl(fvnew, (lane & 7) << 3);
            const int   amg = __shfl(am,    (lane & 7) << 3);
            unsigned pw = (unsigned)amg << (3 * prev);     // field for next = prev(lane)
            pw |= (unsigned)dppmovi<0xB1>((int)pw);
            pw |= (unsigned)dppmovi<0x4E>((int)pw);
            pw |= (unsigned)dppmovi<0x141>((int)pw);
            if (lane == 0) wordL[t] = pw;
            fvp = pv ? nfv : -3.0e38f;
        }

        float term = pv ? (fvp + trans[EOSX * NTAG + prev]) : -3.0e38f;
        int am = prev;
        {
            const float om = dppmovf<0xB1>(term); const int oa = dppmovi<0xB1>(am);
            if (om > term || (om == term && oa < am)) { term = om; am = oa; }
        }
        {
            const float om = dppmovf<0x4E>(term); const int oa = dppmovi<0x4E>(am);
            if (om > term || (om == term && oa < am)) { term = om; am = oa; }
        }
        {
            const float om = dppmovf<0x141>(term); const int oa = dppmovi<0x141>(am);
            if (om > term || (om == term && oa < am)) { term = om; am = oa; }
        }
        if (lane == 0) out[b] = term;

        // ---- backtrace: preload packed words, uniform readlane bit-chase ----
        unsigned wd[8];
        #pragma unroll
        for (int c2 = 0; c2 < 8; ++c2) wd[c2] = wordL[c2 * 64 + lane];
        int cur = __builtin_amdgcn_readfirstlane(am);      // uniform terminal tag
        unsigned pr[8];
        #pragma unroll
        for (int c2 = 7; c2 >= 0; --c2) {                  // unrolled: wd/pr static-indexed
            unsigned acc = 0u;
            for (int tt = 63; tt >= 0; --tt) {             // t = c2*64 + tt, descending
                acc = (lane == tt) ? (unsigned)cur : acc;  // path[t] = cur
                const unsigned w = (unsigned)__builtin_amdgcn_readlane((int)wd[c2], tt);
                cur = (int)((w >> (3 * cur)) & 7u);        // cur = bptr[t][cur]
            }
            pr[c2] = acc;
        }
        #pragma unroll
        for (int c2 = 0; c2 < 8; ++c2)
            out[BSZ + (c2 * 64 + lane) * BSZ + b] = (float)pr[c2];
    }
}

// ======================= launch =======================
extern "C" void kernel_launch(void* const* d_in, const int* in_sizes, int n_in,
                              void* d_out, int out_size, void* d_ws, size_t ws_size,
                              hipStream_t stream)
{
    const int*   sen   = (const int*)d_in[0];
    const float* emb   = (const float*)d_in[1];
    const float* Wih_f = (const float*)d_in[2];
    const float* Whh_f = (const float*)d_in[3];
    const float* b_f   = (const float*)d_in[4];
    const float* Wih_b = (const float*)d_in[5];
    const float* Whh_b = (const float*)d_in[6];
    const float* b_b   = (const float*)d_in[7];
    const float* W_out = (const float*)d_in[8];
    const float* b_out = (const float*)d_in[9];
    const float* trans = (const float*)d_in[10];
    float* out = (float*)d_out;

    char* ws = (char*)d_ws;
    const size_t ft_bytes = (size_t)BSZ * SEQ * 8 * 4;    // 2 MB each
    float* eft = (float*)ws;
    float* ebt = (float*)(ws + ft_bytes);

    bilstm_fused<<<dim3(2 * BSZ), dim3(1024), 0, stream>>>(
        sen, emb, Wih_f, b_f, Wih_b, b_b, Whh_f, Whh_b, W_out, eft, ebt);
    vit_kernel<<<dim3(BSZ), dim3(256), 0, stream>>>(eft, ebt, b_out, trans, out);
}

// Round 12
// 553.217 us; speedup vs baseline: 1.1133x; 1.1133x over previous
//
#include <hip/hip_runtime.h>
#include <hip/hip_bf16.h>
#include <math.h>

#define SEQ  512
#define BSZ  128
#define EMBD 128
#define H4   512
#define HD   128
#define NTAG 7
#define BOSX 4
#define EOSX 5
#define NEGC (-10000.0f)

typedef _Float16 h2 __attribute__((ext_vector_type(2)));
typedef _Float16 f16x8 __attribute__((ext_vector_type(8)));
typedef float    f32x4 __attribute__((ext_vector_type(4)));

__device__ __forceinline__ float frcp(float x) { return __builtin_amdgcn_rcpf(x); }

// f16 dot2: 2 MACs/inst, fp32 accumulate (v_dot2_f32_f16)
__device__ __forceinline__ float fdot2(h2 a, h2 b, float c) {
#if __has_builtin(__builtin_amdgcn_fdot2)
    return __builtin_amdgcn_fdot2(a, b, c, false);
#else
    return c + (float)a.x * (float)b.x + (float)a.y * (float)b.y;
#endif
}

template<int C> __device__ __forceinline__ float dppaddf(float x) {
    const int y = __builtin_amdgcn_update_dpp(0, __builtin_bit_cast(int, x), C, 0xF, 0xF, true);
    return x + __builtin_bit_cast(float, y);
}
template<int C> __device__ __forceinline__ float dppmovf(float x) {
    return __builtin_bit_cast(float,
        __builtin_amdgcn_update_dpp(0, __builtin_bit_cast(int, x), C, 0xF, 0xF, true));
}
template<int C> __device__ __forceinline__ int dppmovi(int x) {
    return __builtin_amdgcn_update_dpp(0, x, C, 0xF, 0xF, true);
}
// k = lane bits {0,1}: full k-reduce = 2 DPP stages
__device__ __forceinline__ float kreduce4(float x) {
    x = dppaddf<0xB1>(x);   // xor bit0
    x = dppaddf<0x4E>(x);   // xor bit1
    return x;
}

// f16 chunk layout for h (recurrence dot operand): chunk k = 32 f16 = 16
// dwords at dword offset 20*k; conflict-free b128 reads (round-1 notes).
#define CH_DW  20
#define ROW_DW 80

// 32-element f16 chunk dot: w[16] half2 x x[16] half2 -> fp32
__device__ __forceinline__ float dot32h(const h2* __restrict__ w, const h2* __restrict__ x) {
    float a = 0.f;
    #pragma unroll
    for (int j = 0; j < 16; ++j) a = fdot2(w[j], x[j], a);
    return a;
}
// load 32 fp32 weights -> 16 half2 (RNE, one-time)
__device__ __forceinline__ void ldwh(h2* w, const float4* wr) {
    #pragma unroll
    for (int j = 0; j < 8; ++j) {
        const float4 f4 = wr[j];
        h2 a; a.x = (_Float16)f4.x; a.y = (_Float16)f4.y;
        h2 b; b.x = (_Float16)f4.z; b.y = (_Float16)f4.w;
        w[2 * j] = a; w[2 * j + 1] = b;
    }
}
__device__ __forceinline__ void unp16(const uint4* p, h2* x) {
    #pragma unroll
    for (int j = 0; j < 4; ++j) {
        x[4 * j]     = __builtin_bit_cast(h2, p[j].x);
        x[4 * j + 1] = __builtin_bit_cast(h2, p[j].y);
        x[4 * j + 2] = __builtin_bit_cast(h2, p[j].z);
        x[4 * j + 3] = __builtin_bit_cast(h2, p[j].w);
    }
}

// step barrier WITHOUT the vmcnt(0)/expcnt drain __syncthreads forces:
// LDS producers (h/zb/xA ds_writes) drain via lgkmcnt(0); global loads/stores
// stay in flight across the barrier (counted vmcnt waits appear at uses).
// sched_barrier(0) fences pin LDS ops on the correct side (rule #18).
// Correctness-proven in round 9 (refcheck pass).
__device__ __forceinline__ void step_barrier() {
    __builtin_amdgcn_sched_barrier(0);
    asm volatile("s_waitcnt lgkmcnt(0)" ::: "memory");
    __builtin_amdgcn_s_barrier();
    __builtin_amdgcn_sched_barrier(0);
}

// =============== K1: round-7 structure (measured optimum, 370 us) ============
// MFMA-batched projection + VALU recurrence. Session bracket (rounds 4-11):
// MFMA recurrence worse (+7%), pipelining null x2, register-budget null x2,
// TLP at 4 waves/SIMD worse (+20%), local shaves -1.7% -> this configuration
// is the measured optimum of the decomposition. Two local shaves on top of
// round 7:
//  (a) lgkm-only step barrier (no vmcnt drain: emission stores + token loads
//      stay in flight across barriers),
//  (b) zq ping-pong: the per-step dependent zb read moves off the critical
//      path (step s prefetches step s+1's z; window-boundary buffer validity:
//      next window's rows are written at the PREVIOUS window's sl==0 proj,
//      8 barriers before the sl==7 prefetch that first reads them).
__global__ __launch_bounds__(512) __attribute__((amdgpu_waves_per_eu(1, 2)))
void bilstm_fused(const int* __restrict__ sen, const float* __restrict__ emb,
                  const float* __restrict__ Wih_f, const float* __restrict__ b_f,
                  const float* __restrict__ Wih_b, const float* __restrict__ b_b,
                  const float* __restrict__ Whh_f, const float* __restrict__ Whh_b,
                  const float* __restrict__ W_out,
                  float* __restrict__ eft, float* __restrict__ ebt)
{
    const int tid = threadIdx.x;
    const int wid = tid >> 6;
    const int lane = tid & 63;
    const int k = lane & 3;                                // K-chunk / owned gate q
    const int m = lane >> 2;                               // 0..15
    const int u = wid * 16 + m;
    const bool bk0 = (lane & 1) != 0;
    const bool bk1 = (lane & 2) != 0;
    const int col = lane & 15;                             // MFMA N-col / A-row
    const int kg  = lane >> 4;                             // MFMA K-group
    const int chain = blockIdx.x;
    const int dir = chain & 1;
    const int b = chain >> 1;
    const int t0 = dir ? (SEQ - 1) : 0;
    const int ts = dir ? -1 : 1;

    __shared__ __align__(16) _Float16 xA[2][4][4][16][8];  // x A-frag dbuf, 8 KB
    __shared__ __align__(16) float zb[2][8][512];          // z (proj+bias) dbuf, 32 KB
    __shared__ __align__(16) unsigned hdb_u[2 * ROW_DW];   // h double-buffer, f16 chunks

    const float* __restrict__ Wih  = dir ? Wih_b : Wih_f;
    const float* __restrict__ Whh  = dir ? Whh_b : Whh_f;
    const float* __restrict__ bias = dir ? b_b  : b_f;

    // recurrence weights (dot layout) + emission weights
    h2 whh[4][16], wo[16];
    #pragma unroll
    for (int g = 0; g < 4; ++g)
        ldwh(whh[g], (const float4*)(Whh + (g * HD + u) * HD + k * 32));
    {
        const int mm = (m < NTAG) ? m : 0;
        ldwh(wo, (const float4*)(W_out + mm * 256 + dir * HD + k * 32));
    }
    // projection weights as MFMA B-fragments: tile tt covers gate-rows
    // R=(wid*4+tt)*16+col; frag ks holds k = ks*32 + kg*8 + j  [r2/r7 verified]
    f16x8 bw[4][4];
    float biasv[4];
    #pragma unroll
    for (int tt = 0; tt < 4; ++tt) {
        const int R = (wid * 4 + tt) * 16 + col;
        const int ug = R >> 2;
        const int gg = R & 3;
        #pragma unroll
        for (int ks = 0; ks < 4; ++ks) {
            const float* src = Wih + (gg * HD + ug) * EMBD + ks * 32 + kg * 8;
            f16x8 v;
            #pragma unroll
            for (int j = 0; j < 8; ++j) v[j] = (_Float16)src[j];
            bw[tt][ks] = v;
        }
        biasv[tt] = bias[gg * HD + ug];
    }

    if (tid < 2 * ROW_DW) hdb_u[tid] = 0u;                 // h=0
    {   // zero xA (rows 8..15 never staged; keep MFMA inputs finite)
        unsigned* p = (unsigned*)xA;                       // 2048 dwords
        p[tid] = 0u; p[tid + 512] = 0u; p[tid + 1024] = 0u; p[tid + 1536] = 0u;
    }

    // ---- x staging: window w = rows [8w,8w+8); wave srow stages row 8w+srow,
    // lane sp loads float2 (k=2sp) -> one dword of the A-frag layout:
    // ks=sp>>4, kg=(sp>>2)&3, j=(sp&3)*2 ----
    const int srow = wid;
    const int sp = lane;
    float2 sv;                                             // in-flight window regs
    auto sissue = [&](int w) {
        const int row = w * 8 + srow;
        const int tg = t0 + ts * row;
        const int tok = sen[tg * BSZ + b];
        sv = *(const float2*)(emb + (size_t)tok * EMBD + 2 * sp);
    };
    auto swrite = [&](int buf) {
        h2 t; t.x = (_Float16)sv.x; t.y = (_Float16)sv.y;
        *(unsigned*)&xA[buf][sp >> 4][(sp >> 2) & 3][srow][(sp & 3) * 2]
            = __builtin_bit_cast(unsigned, t);
    };

    // ---- batched projection: 16 MFMA -> z rows 0..7 of buffer nb ----
    auto proj = [&](int bufp, int nb) {
        f16x8 ax[4];
        #pragma unroll
        for (int ks = 0; ks < 4; ++ks)
            ax[ks] = *(const f16x8*)&xA[bufp][ks][kg][col][0];
        f32x4 acc[4];
        #pragma unroll
        for (int tt = 0; tt < 4; ++tt) { acc[tt][0]=0.f; acc[tt][1]=0.f; acc[tt][2]=0.f; acc[tt][3]=0.f; }
        #pragma unroll
        for (int ks = 0; ks < 4; ++ks)
            #pragma unroll
            for (int tt = 0; tt < 4; ++tt)
                acc[tt] = __builtin_amdgcn_mfma_f32_16x16x32_f16(ax[ks], bw[tt][ks], acc[tt], 0, 0, 0);
        if (lane < 32) {                                   // D rows 0..7 = time rows
            #pragma unroll
            for (int tt = 0; tt < 4; ++tt)
                #pragma unroll
                for (int r = 0; r < 4; ++r)
                    zb[nb][(lane >> 4) * 4 + r][wid * 64 + tt * 16 + col]
                        = acc[tt][r] + biasv[tt];
        }
    };

    float c = 0.0f, v0 = 0.0f, v1 = 0.0f, v2 = 0.0f, v3 = 0.0f;
    float zqA, zqB;                                        // z ping-pong regs
    float* __restrict__ eX = (dir ? ebt : eft) + (size_t)b * (SEQ * 8);

    // ---- prologue: stage windows 0,1; proj window0 -> zb[0]; window 2 in flight
    sissue(0); swrite(0);
    sissue(1); swrite(1);
    __syncthreads();
    proj(0, 0);                                            // z rows 0..7
    sissue(2);
    __syncthreads();
    zqA = zb[0][0][wid * 64 + lane];                       // z for step 0

    // ---- main loop: 64 blocks of 8 steps, one lgkm-only barrier/step ----
    for (int base = 0; base < SEQ; base += 8) {
        const int W = base >> 3;
        #pragma unroll
        for (int sl = 0; sl < 8; ++sl) {
            const int s = base + sl;
            const int cur = sl & 1;                        // base even -> s&1 == sl&1
            // h-read for this step (chunk k of h_{t-ts})
            uint4 hpk[4];
            {
                const uint4* hr = (const uint4*)(hdb_u + cur * ROW_DW + k * CH_DW);
                #pragma unroll
                for (int j = 0; j < 4; ++j) hpk[j] = hr[j];
            }
            if (sl == 0) {
                if (base <= SEQ - 24) swrite(W & 1);       // window W+2 -> buf W&1
                if (base <= SEQ - 32) sissue(W + 3);       // rows [base+24,base+32)
                if (W < 63) proj((W & 1) ^ 1, (W & 1) ^ 1);// z rows base+8..15
            }
            const float xq = (sl & 1) ? zqB : zqA;         // z for THIS step (prefetched)
            // prefetch z for step s+1 (independent LDS read, overlaps the dots)
            if (s + 1 < SEQ) {
                const int nbuf = (sl == 7) ? ((W & 1) ^ 1) : (W & 1);
                const int nsl = (sl + 1) & 7;
                const float zn = zb[nbuf][nsl][wid * 64 + lane];
                if (sl & 1) zqA = zn; else zqB = zn;
            }
            // recurrence
            h2 hx[16];
            unp16(hpk, hx);
            {
                const float pi = dot32h(whh[0], hx);
                const float pf = dot32h(whh[1], hx);
                const float pg = dot32h(whh[2], hx);
                const float po = dot32h(whh[3], hx);
                const float A = (bk0 ? pf : pi) + dppmovf<0xB1>(bk0 ? pi : pf);
                const float B = (bk0 ? po : pg) + dppmovf<0x4E>(bk0 ? pg : po);
                float z = (bk1 ? B : A) + dppmovf<0x4E>(bk1 ? A : B);
                z += xq;
                // one activation per lane (gate 2 = tanh via 2*sigma(2z)-1)
                const bool isg = bk1 && !bk0;
                const float x2 = isg ? (z + z) : z;
                float y = frcp(1.0f + __expf(-x2));
                y = isg ? (2.0f * y - 1.0f) : y;
                // all-gather the 4 activated gates
                const float r1 = dppmovf<0xB1>(y);
                const float r2 = dppmovf<0x4E>(y);
                const float r3 = dppmovf<0x4E>(r1);
                const float i0 = bk0 ? r1 : y,  i1 = bk0 ? y : r1;
                const float i2 = bk0 ? r3 : r2, i3 = bk0 ? r2 : r3;
                const float gi = bk1 ? i2 : i0;
                const float gf = bk1 ? i3 : i1;
                const float gg2 = bk1 ? i0 : i2;
                const float go = bk1 ? i1 : i3;
                c = gf * c + gi * gg2;                     // redundant across 4 k-lanes
                const float th = 2.0f * frcp(1.0f + __expf(-2.0f * c)) - 1.0f;
                const float h = go * th;
                if (k == 0) {                              // write h as f16 halfword
                    ((unsigned short*)hdb_u)[((cur ^ 1) * ROW_DW + (u >> 5) * CH_DW) * 2 + (u & 31)]
                        = __builtin_bit_cast(unsigned short, (_Float16)h);
                }
            }
            if (wid == 0 && s >= 1) {                      // emission for time e = s-1
                const float ev = kreduce4(dot32h(wo, hx));
                const int e = s - 1;
                const bool mine = (e & 3) == k;            // e uniform, k lane-varying
                const int j = (e >> 2) & 3;
                v0 = (mine && j == 0) ? ev : v0;
                v1 = (mine && j == 1) ? ev : v1;
                v2 = (mine && j == 2) ? ev : v2;
                v3 = (mine && j == 3) ? ev : v3;
                if ((s & 15) == 0 && m < NTAG) {           // flush e in [s-16, s-1]
                    const int eA = s - 16 + k;
                    eX[(t0 + ts * (eA +  0)) * 8 + m] = v0;
                    eX[(t0 + ts * (eA +  4)) * 8 + m] = v1;
                    eX[(t0 + ts * (eA +  8)) * 8 + m] = v2;
                    eX[(t0 + ts * (eA + 12)) * 8 + m] = v3;
                }
            }
            step_barrier();
        }
    }

    // ---- epilogue: s = SEQ -> emission e = SEQ-1 + final flush ----
    {
        h2 hx[16];                                         // h_{last} from hdb[0]
        const uint4* hr = (const uint4*)(hdb_u + k * CH_DW);
        uint4 pk[4];
        #pragma unroll
        for (int j = 0; j < 4; ++j) pk[j] = hr[j];
        unp16(pk, hx);
        if (wid == 0) {
            const float ev = kreduce4(dot32h(wo, hx));
            if (k == 3) v3 = ev;                           // e=511: (e&3)=3, (e>>2)&3=3
            if (m < NTAG) {
                const int eA = SEQ - 16 + k;
                eX[(t0 + ts * (eA +  0)) * 8 + m] = v0;
                eX[(t0 + ts * (eA +  4)) * 8 + m] = v1;
                eX[(t0 + ts * (eA +  8)) * 8 + m] = v2;
                eX[(t0 + ts * (eA + 12)) * 8 + m] = v3;
            }
        }
    }
}

// ======================= K2: Viterbi scan + backtrace =======================
// (verbatim round-4 kernel: DPP butterfly argmax, OR-packed 3-bit
// backpointer words, readlane-only bit-chase backtrace)
__global__ __launch_bounds__(256, 1)
void vit_kernel(const float* __restrict__ eft, const float* __restrict__ ebt,
                const float* __restrict__ b_out, const float* __restrict__ trans,
                float* __restrict__ out)
{
    const int b = blockIdx.x;
    const int tid = threadIdx.x;
    __shared__ __align__(16) float ftl[SEQ * 8];
    __shared__ unsigned wordL[SEQ];                        // packed backpointers

    {   // stage ef+eb with all 256 threads
        const float4* sf = (const float4*)(eft + (size_t)b * (SEQ * 8));
        const float4* sb = (const float4*)(ebt + (size_t)b * (SEQ * 8));
        float4* dst = (float4*)ftl;
        #pragma unroll
        for (int i = 0; i < SEQ * 2 / 256; ++i) {
            const int idx = tid + i * 256;
            float4 a = sf[idx];
            const float4 c4 = sb[idx];
            a.x += c4.x; a.y += c4.y; a.z += c4.z; a.w += c4.w;
            dst[idx] = a;
        }
    }
    __syncthreads();

    if (tid < 64) {
        const int lane = tid;
        const int next = lane >> 3;
        const int prev = lane & 7;
        const bool pv = (prev < NTAG);
        const bool nv = (next < NTAG);
        const float trv = (pv && nv) ? (trans[next * NTAG + prev] + b_out[next]) : -3.0e38f;
        float fvp = pv ? ((prev == BOSX) ? 0.0f : NEGC) : -3.0e38f;

        // (max, first-index) combiner is associative+commutative ->
        // any butterfly pairing gives results identical to the shfl version.
        for (int t = 0; t < SEQ; ++t) {
            float mv = fvp + trv;
            int am = prev;
            {   // xor1 (quad_perm)
                const float om = dppmovf<0xB1>(mv); const int oa = dppmovi<0xB1>(am);
                if (om > mv || (om == mv && oa < am)) { mv = om; am = oa; }
            }
            {   // xor2 (quad_perm)
                const float om = dppmovf<0x4E>(mv); const int oa = dppmovi<0x4E>(am);
                if (om > mv || (om == mv && oa < am)) { mv = om; am = oa; }
            }
            {   // quad-pair via row_half_mirror (value quad-uniform by now)
                const float om = dppmovf<0x141>(mv); const int oa = dppmovi<0x141>(am);
                if (om > mv || (om == mv && oa < am)) { mv = om; am = oa; }
            }
            const float fvnew = mv + ftl[t * 8 + next];
            // transpose: fvp[lane] = fvnew(next = prev(lane)); same pattern
            // gathers am so lane holds bptr[next = prev(lane)]
            const float nfv = __shfl(fvnew, (lane & 7) << 3);
            const int   amg = __shfl(am,    (lane & 7) << 3);
            unsigned pw = (unsigned)amg << (3 * prev);     // field for next = prev(lane)
            pw |= (unsigned)dppmovi<0xB1>((int)pw);
            pw |= (unsigned)dppmovi<0x4E>((int)pw);
            pw |= (unsigned)dppmovi<0x141>((int)pw);
            if (lane == 0) wordL[t] = pw;
            fvp = pv ? nfv : -3.0e38f;
        }

        float term = pv ? (fvp + trans[EOSX * NTAG + prev]) : -3.0e38f;
        int am = prev;
        {
            const float om = dppmovf<0xB1>(term); const int oa = dppmovi<0xB1>(am);
            if (om > term || (om == term && oa < am)) { term = om; am = oa; }
        }
        {
            const float om = dppmovf<0x4E>(term); const int oa = dppmovi<0x4E>(am);
            if (om > term || (om == term && oa < am)) { term = om; am = oa; }
        }
        {
            const float om = dppmovf<0x141>(term); const int oa = dppmovi<0x141>(am);
            if (om > term || (om == term && oa < am)) { term = om; am = oa; }
        }
        if (lane == 0) out[b] = term;

        // ---- backtrace: preload packed words, uniform readlane bit-chase ----
        unsigned wd[8];
        #pragma unroll
        for (int c2 = 0; c2 < 8; ++c2) wd[c2] = wordL[c2 * 64 + lane];
        int cur = __builtin_amdgcn_readfirstlane(am);      // uniform terminal tag
        unsigned pr[8];
        #pragma unroll
        for (int c2 = 7; c2 >= 0; --c2) {                  // unrolled: wd/pr static-indexed
            unsigned acc = 0u;
            for (int tt = 63; tt >= 0; --tt) {             // t = c2*64 + tt, descending
                acc = (lane == tt) ? (unsigned)cur : acc;  // path[t] = cur
                const unsigned w = (unsigned)__builtin_amdgcn_readlane((int)wd[c2], tt);
                cur = (int)((w >> (3 * cur)) & 7u);        // cur = bptr[t][cur]
            }
            pr[c2] = acc;
        }
        #pragma unroll
        for (int c2 = 0; c2 < 8; ++c2)
            out[BSZ + (c2 * 64 + lane) * BSZ + b] = (float)pr[c2];
    }
}

// ======================= launch =======================
extern "C" void kernel_launch(void* const* d_in, const int* in_sizes, int n_in,
                              void* d_out, int out_size, void* d_ws, size_t ws_size,
                              hipStream_t stream)
{
    const int*   sen   = (const int*)d_in[0];
    const float* emb   = (const float*)d_in[1];
    const float* Wih_f = (const float*)d_in[2];
    const float* Whh_f = (const float*)d_in[3];
    const float* b_f   = (const float*)d_in[4];
    const float* Wih_b = (const float*)d_in[5];
    const float* Whh_b = (const float*)d_in[6];
    const float* b_b   = (const float*)d_in[7];
    const float* W_out = (const float*)d_in[8];
    const float* b_out = (const float*)d_in[9];
    const float* trans = (const float*)d_in[10];
    float* out = (float*)d_out;

    char* ws = (char*)d_ws;
    const size_t ft_bytes = (size_t)BSZ * SEQ * 8 * 4;    // 2 MB each
    float* eft = (float*)ws;
    float* ebt = (float*)(ws + ft_bytes);

    bilstm_fused<<<dim3(2 * BSZ), dim3(512), 0, stream>>>(
        sen, emb, Wih_f, b_f, Wih_b, b_b, Whh_f, Whh_b, W_out, eft, ebt);
    vit_kernel<<<dim3(BSZ), dim3(256), 0, stream>>>(eft, ebt, b_out, trans, out);
}